// Round 1
// baseline (1034.496 us; speedup 1.0000x reference)
//
#include <hip/hip_runtime.h>
#include <math.h>

// ---------------------------------------------------------------------------
// RetentionBlock: LN1 -> QKVG proj -> retention scan -> Wo + residual ->
//                 LN2 -> FFN(gelu) + residual
// B=4, L=4096, D_MODEL=1024, H=16, DH=64. All global inputs f32.
// R9: GEMM rewritten to the 256^2 8-phase template (learn_hip m201):
//     512 thr / 8 waves (2Mx4N), BK=64, 128 KiB LDS double buffer,
//     per-phase {ds_read || stage-issue -> s_barrier -> setprio(1) ->
//     16 MFMA -> setprio(0) -> s_barrier}, vmcnt drain ONCE per K-tile
//     (__syncthreads at tile boundary) instead of per 16 MFMAs.
//     LDS-read minimized: A frags resident per row-half, B frags resident
//     for the whole tile -> 24 ds_read_b128 / tile / wave (template: 48).
//     Swizzle: col ^= (row&7)<<3 applied to global SOURCE of
//     global_load_lds (linear dest) and to ds_read addresses (rule #21).
// ---------------------------------------------------------------------------

#define D_MODEL 1024
#define LSEQ    4096
#define BATCH   4
#define NROWS   (BATCH * LSEQ)      // 16384
#define HEADS   16
#define DH      64
#define CHUNK   128
#define NCH     (LSEQ / CHUNK)      // 32

typedef short  short8  __attribute__((ext_vector_type(8)));
typedef short  short4v __attribute__((ext_vector_type(4)));
typedef float  float4v __attribute__((ext_vector_type(4)));

__device__ inline short f2bf(float f) {
    unsigned u = __float_as_uint(f);
    u += 0x7fffu + ((u >> 16) & 1u);   // round-to-nearest-even
    return (short)(u >> 16);
}
__device__ inline float bf2f(short s) {
    return __uint_as_float(((unsigned)(unsigned short)s) << 16);
}

// async global->LDS, 16 bytes per lane; dest = wave-uniform base + lane*16
__device__ inline void load_lds16(const short* g, short* l) {
    __builtin_amdgcn_global_load_lds(
        (const __attribute__((address_space(1))) void*)g,
        (__attribute__((address_space(3))) void*)l,
        16, 0, 0);
}

// ---------------------------------------------------------------------------
// Transpose f32 [R][C] -> bf16 [C][R]
// ---------------------------------------------------------------------------
__global__ __launch_bounds__(1024) void transpose_f32_bf16(
    const float* __restrict__ in, short* __restrict__ out, int R, int C)
{
    __shared__ float tile[32][33];
    int tx = threadIdx.x, ty = threadIdx.y;
    int r = blockIdx.y * 32 + ty;
    int c = blockIdx.x * 32 + tx;
    tile[ty][tx] = in[(size_t)r * C + c];
    __syncthreads();
    out[(size_t)(blockIdx.x * 32 + ty) * R + blockIdx.y * 32 + tx] =
        f2bf(tile[tx][ty]);
}

// concat bq|bk|bv|bg -> bias_qkvg[4096]
__global__ __launch_bounds__(256) void concat_bias(
    const float* __restrict__ bq, const float* __restrict__ bk,
    const float* __restrict__ bv, const float* __restrict__ bg,
    float* __restrict__ out)
{
    int i = blockIdx.x * 256 + threadIdx.x;
    const float* src = (i < 1024) ? bq : (i < 2048) ? bk : (i < 3072) ? bv : bg;
    out[i] = src[i & 1023];
}

// ---------------------------------------------------------------------------
// Row LayerNorm: f32 [row][1024] -> bf16 [row][1024]. 1 block / row.
// ---------------------------------------------------------------------------
__global__ __launch_bounds__(256) void ln_kernel(
    const float* __restrict__ x, const float* __restrict__ g,
    const float* __restrict__ b, short* __restrict__ y)
{
    int row = blockIdx.x;
    int tid = threadIdx.x;
    const float4* xr = (const float4*)(x + (size_t)row * D_MODEL);
    float4 v = xr[tid];
    float s  = v.x + v.y + v.z + v.w;
    float ss = v.x * v.x + v.y * v.y + v.z * v.z + v.w * v.w;
    #pragma unroll
    for (int off = 32; off > 0; off >>= 1) {
        s  += __shfl_down(s, off);
        ss += __shfl_down(ss, off);
    }
    __shared__ float sbuf[8];
    int wv = tid >> 6, ln = tid & 63;
    if (ln == 0) { sbuf[wv] = s; sbuf[4 + wv] = ss; }
    __syncthreads();
    float tot  = sbuf[0] + sbuf[1] + sbuf[2] + sbuf[3];
    float tot2 = sbuf[4] + sbuf[5] + sbuf[6] + sbuf[7];
    float mu  = tot * (1.0f / D_MODEL);
    float var = tot2 * (1.0f / D_MODEL) - mu * mu;
    float rs  = rsqrtf(var + 1e-5f);
    float4 gg = ((const float4*)g)[tid];
    float4 bb = ((const float4*)b)[tid];
    short4v o;
    o.x = f2bf((v.x - mu) * rs * gg.x + bb.x);
    o.y = f2bf((v.y - mu) * rs * gg.y + bb.y);
    o.z = f2bf((v.z - mu) * rs * gg.z + bb.z);
    o.w = f2bf((v.w - mu) * rs * gg.w + bb.w);
    ((short4v*)y)[(size_t)row * 256 + tid] = o;
}

// ---------------------------------------------------------------------------
// bf16 MFMA GEMM, 256x256 tile, 8-phase schedule (m201 template).
// C[M][N] = A[M][K](bf16) * BT[N][K](bf16)^T, fused epilogue.
// Block 512 = 8 waves as 2(M) x 4(N); wave owns 128x64 = 8x4 frags 16x16x32.
// LDS: As/Bs [2 dbuf][256 rows][64 k] bf16, 128 KiB total, 1 block/CU.
// LDS layout: element (r,c) at linear r*64 + (c ^ ((r&7)<<3)); staged via
// linear-dest global_load_lds with the inverse XOR folded into the SOURCE
// column; ds_read applies the same XOR -> conflict-free b128 reads.
// Phases per K-tile (BK=64): p0: read A(qr0)+B(qc0), stage A(t+1), mfma Q00;
//   p1: read B(qc1), stage B(t+1), mfma Q01; p2: read A(qr1), mfma Q10;
//   p3: mfma Q11, __syncthreads (vmcnt drain once per tile).
// mode 0: out_bf16 = (col>=3072 ? sigmoid : id)(acc + bias)        [QKVG]
// mode 1: out_f32  = acc + bias + res   (res==outf in-place is OK) [x2 / final]
// mode 2: out_bf16 = gelu_exact(acc + bias)                        [FFN mid]
// ---------------------------------------------------------------------------
__global__ __launch_bounds__(512, 2) void gemm_bf16(
    const short* __restrict__ A, const short* __restrict__ BT,
    const float* __restrict__ bias, const float* __restrict__ res,
    float* __restrict__ outf, short* __restrict__ outb,
    int M, int N, int K, int mode)
{
    __shared__ short As[2][16384];   // [dbuf][256*64]
    __shared__ short Bs[2][16384];

    // ---- XCD-bijective swizzle (nwg % 8 == 0 for all our launches),
    //      then M-major decode: 64 consecutive wg share one 256-col B strip.
    const int gx  = gridDim.x;                       // 64 (M blocks)
    const int nwg = gx * gridDim.y;
    const int lin = blockIdx.x + blockIdx.y * gx;
    const int cpx = nwg >> 3;
    const int wg  = (lin & 7) * cpx + (lin >> 3);
    const int bx  = wg % gx;
    const int by  = wg / gx;
    const int row0 = bx * 256;
    const int col0 = by * 256;

    const int tid  = threadIdx.x;
    const int wave = tid >> 6;
    const int lane = tid & 63;
    const int wm   = wave >> 2;          // 0..1  (row half of 256)
    const int wn   = wave & 3;           // 0..3  (64-col strip)
    const int lm   = lane & 15;          // row within 16-tile
    const int q    = lane >> 4;          // k-group 0..3
    const int kq0  = ((q ^ (lm & 7)) << 3);          // ks=0 col offset (elems)
    // ks=1 offset = kq0 ^ 32

    // ---- staging: thread covers rows (tid>>3)+{0,64,128,192}, 8 elems each;
    //      source column pre-swizzled so linear LDS dest == swizzled layout.
    const int csw = (((tid & 7) ^ ((tid >> 3) & 7)) << 3);
    const short* gA = A  + (size_t)(row0 + (tid >> 3)) * K + csw;
    const short* gB = BT + (size_t)(col0 + (tid >> 3)) * K + csw;
    short* sA = &As[0][0] + tid * 8;
    short* sB = &Bs[0][0] + tid * 8;
    const size_t K64 = (size_t)64 * K;

    float4v acc[8][4];
    #pragma unroll
    for (int i = 0; i < 8; i++)
        #pragma unroll
        for (int j = 0; j < 4; j++)
            acc[i][j] = (float4v)(0.0f);

    const int NT = K >> 6;

    // ---- prologue: stage tile 0 -> buf 0, full drain
    load_lds16(gA,            sA);
    load_lds16(gA +     K64,  sA + 4096);
    load_lds16(gA + 2 * K64,  sA + 8192);
    load_lds16(gA + 3 * K64,  sA + 12288);
    load_lds16(gB,            sB);
    load_lds16(gB +     K64,  sB + 4096);
    load_lds16(gB + 2 * K64,  sB + 8192);
    load_lds16(gB + 3 * K64,  sB + 12288);
    __syncthreads();

    const short* Abase = &As[0][0] + wm * 8192;          // + buf*16384
    const short* Bbase = &Bs[0][0] + (wn >> 1) * 8192;   // + buf*16384
    const int aro = lm * 64;                             // + (qr*64+i*16)*64
    const int bro = ((wn & 1) * 64 + lm) * 64;           // + (qc*32+j*16)*64

    short8 aF[4][2];        // A frags for current qr      (resident 2 phases)
    short8 bF[2][2][2];     // B frags [qc][j][ks]         (resident all tile)

#define MFMA8(QR, QC)                                                        \
    _Pragma("unroll")                                                        \
    for (int ks = 0; ks < 2; ks++)                                           \
        _Pragma("unroll")                                                    \
        for (int i = 0; i < 4; i++)                                          \
            _Pragma("unroll")                                                \
            for (int j = 0; j < 2; j++)                                      \
                acc[(QR) * 4 + i][(QC) * 2 + j] =                            \
                    __builtin_amdgcn_mfma_f32_16x16x32_bf16(                 \
                        aF[i][ks], bF[QC][j][ks],                            \
                        acc[(QR) * 4 + i][(QC) * 2 + j], 0, 0, 0);

    for (int t = 0; t < NT; ++t) {
        const int bufo = (t & 1) << 14;              // *16384
        const short* Ab = Abase + bufo;
        const short* Bb = Bbase + bufo;
        const int  kb = (t + 1) << 6;
        const bool pf = (t + 1 < NT);
        const int  pfo = ((t + 1) & 1) << 14;

        // -------- phase 0: read A(qr0) + B(qc0); stage A(t+1); mfma Q00
        #pragma unroll
        for (int i = 0; i < 4; i++) {
            const int ar = aro + (i * 16) * 64;
            aF[i][0] = *(const short8*)&Ab[ar + kq0];
            aF[i][1] = *(const short8*)&Ab[ar + (kq0 ^ 32)];
        }
        #pragma unroll
        for (int j = 0; j < 2; j++) {
            const int br = bro + (j * 16) * 64;
            bF[0][j][0] = *(const short8*)&Bb[br + kq0];
            bF[0][j][1] = *(const short8*)&Bb[br + (kq0 ^ 32)];
        }
        if (pf) {
            short* d = sA + pfo;
            load_lds16(gA + kb,            d);
            load_lds16(gA +     K64 + kb,  d + 4096);
            load_lds16(gA + 2 * K64 + kb,  d + 8192);
            load_lds16(gA + 3 * K64 + kb,  d + 12288);
        }
        __builtin_amdgcn_s_barrier();
        __builtin_amdgcn_s_setprio(1);
        MFMA8(0, 0)
        __builtin_amdgcn_s_setprio(0);
        __builtin_amdgcn_s_barrier();

        // -------- phase 1: read B(qc1); stage B(t+1); mfma Q01
        #pragma unroll
        for (int j = 0; j < 2; j++) {
            const int br = bro + (32 + j * 16) * 64;
            bF[1][j][0] = *(const short8*)&Bb[br + kq0];
            bF[1][j][1] = *(const short8*)&Bb[br + (kq0 ^ 32)];
        }
        if (pf) {
            short* d = sB + pfo;
            load_lds16(gB + kb,            d);
            load_lds16(gB +     K64 + kb,  d + 4096);
            load_lds16(gB + 2 * K64 + kb,  d + 8192);
            load_lds16(gB + 3 * K64 + kb,  d + 12288);
        }
        __builtin_amdgcn_s_barrier();
        __builtin_amdgcn_s_setprio(1);
        MFMA8(0, 1)
        __builtin_amdgcn_s_setprio(0);
        __builtin_amdgcn_s_barrier();

        // -------- phase 2: read A(qr1); mfma Q10
        #pragma unroll
        for (int i = 0; i < 4; i++) {
            const int ar = aro + (64 + i * 16) * 64;
            aF[i][0] = *(const short8*)&Ab[ar + kq0];
            aF[i][1] = *(const short8*)&Ab[ar + (kq0 ^ 32)];
        }
        __builtin_amdgcn_s_barrier();
        __builtin_amdgcn_s_setprio(1);
        MFMA8(1, 0)
        __builtin_amdgcn_s_setprio(0);
        __builtin_amdgcn_s_barrier();

        // -------- phase 3: mfma Q11; tile-boundary drain (vmcnt once/tile)
        __builtin_amdgcn_s_setprio(1);
        MFMA8(1, 1)
        __builtin_amdgcn_s_setprio(0);
        __syncthreads();
    }
#undef MFMA8

    // ---- epilogue: C/D layout row=(lane>>4)*4+reg, col=lane&15
    const int r4 = q << 2;
    #pragma unroll
    for (int ai = 0; ai < 8; ai++) {
        const int rowg = row0 + wm * 128 + (ai >> 2) * 64 + (ai & 3) * 16 + r4;
        #pragma unroll
        for (int bj = 0; bj < 4; bj++) {
            const int colg = col0 + wn * 64 + (bj >> 1) * 32 + (bj & 1) * 16 + lm;
            const float bcol = bias[colg];
            #pragma unroll
            for (int r2 = 0; r2 < 4; r2++) {
                size_t idx = (size_t)(rowg + r2) * N + colg;
                float v = acc[ai][bj][r2] + bcol;
                if (mode == 0) {
                    if (colg >= 3072) v = 1.0f / (1.0f + expf(-v));
                    outb[idx] = f2bf(v);
                } else if (mode == 1) {
                    outf[idx] = v + res[idx];
                } else {
                    v = 0.5f * v * (1.0f + erff(v * 0.70710678118654752f));
                    outb[idx] = f2bf(v);
                }
            }
        }
    }
}

// ---------------------------------------------------------------------------
// Retention scan (chunk-parallel). qkvg bf16 [16384][4096]: q|k|v|g sections.
// channel c = b*1024 + h*64 + d  (4096 channels), chunks of 128 timesteps.
// ---------------------------------------------------------------------------
__global__ __launch_bounds__(256) void scan_pass1(
    const short* __restrict__ qkvg, const float* __restrict__ dlogit,
    float* __restrict__ carry)
{
    int j  = blockIdx.x >> 4;
    int c  = ((blockIdx.x & 15) << 8) + threadIdx.x;
    int b  = c >> 10;
    int col = c & 1023;
    float decay = 1.0f / (1.0f + expf(-dlogit[col >> 6]));
    size_t base = ((size_t)b * LSEQ + j * CHUNK) * 4096 + col;
    float s = 0.0f;
    for (int t = 0; t < CHUNK; ++t) {
        float kk = bf2f(qkvg[base + 1024]);
        float vv = bf2f(qkvg[base + 2048]);
        s = decay * s + kk * vv;
        base += 4096;
    }
    carry[j * 4096 + c] = s;
}

__global__ __launch_bounds__(256) void scan_combine(
    const float* __restrict__ carry, const float* __restrict__ dlogit,
    float* __restrict__ sinit)
{
    int c = blockIdx.x * 256 + threadIdx.x;
    float decay = 1.0f / (1.0f + expf(-dlogit[(c & 1023) >> 6]));
    float dp = powf(decay, (float)CHUNK);
    float s = 0.0f;
    for (int j = 0; j < NCH; ++j) {
        sinit[j * 4096 + c] = s;
        s = dp * s + carry[j * 4096 + c];
    }
}

__global__ __launch_bounds__(256) void scan_pass2(
    const short* __restrict__ qkvg, const float* __restrict__ dlogit,
    const float* __restrict__ sinit, short* __restrict__ att)
{
    int j  = blockIdx.x >> 4;
    int c  = ((blockIdx.x & 15) << 8) + threadIdx.x;
    int b  = c >> 10;
    int col = c & 1023;
    float decay = 1.0f / (1.0f + expf(-dlogit[col >> 6]));
    float s = sinit[j * 4096 + c];
    size_t base  = ((size_t)b * LSEQ + j * CHUNK) * 4096 + col;
    size_t obase = ((size_t)b * LSEQ + j * CHUNK) * 1024 + col;
    for (int t = 0; t < CHUNK; ++t) {
        float qq = bf2f(qkvg[base]);
        float kk = bf2f(qkvg[base + 1024]);
        float vv = bf2f(qkvg[base + 2048]);
        float gg = bf2f(qkvg[base + 3072]);
        s = decay * s + kk * vv;
        att[obase] = f2bf(gg * qq * s * 0.125f);   // scale = DH^-0.5
        base += 4096; obase += 1024;
    }
}

// ---------------------------------------------------------------------------
extern "C" void kernel_launch(void* const* d_in, const int* in_sizes, int n_in,
                              void* d_out, int out_size, void* d_ws, size_t ws_size,
                              hipStream_t stream)
{
    const float* x      = (const float*)d_in[0];
    const float* ln1_g  = (const float*)d_in[1];
    const float* ln1_b  = (const float*)d_in[2];
    const float* Wq     = (const float*)d_in[3];
    const float* bq     = (const float*)d_in[4];
    const float* Wk     = (const float*)d_in[5];
    const float* bk     = (const float*)d_in[6];
    const float* Wv     = (const float*)d_in[7];
    const float* bv     = (const float*)d_in[8];
    const float* Wg     = (const float*)d_in[9];
    const float* bg     = (const float*)d_in[10];
    const float* dlog   = (const float*)d_in[11];
    const float* Wo     = (const float*)d_in[12];
    const float* bo     = (const float*)d_in[13];
    const float* ln2_g  = (const float*)d_in[14];
    const float* ln2_b  = (const float*)d_in[15];
    const float* W1     = (const float*)d_in[16];
    const float* b1     = (const float*)d_in[17];
    const float* W2     = (const float*)d_in[18];
    const float* b2     = (const float*)d_in[19];
    float* out = (float*)d_out;

    char* ws = (char*)d_ws;
    size_t off = 0;
    auto alloc = [&](size_t bytes) -> void* {
        void* p = ws + off;
        off += (bytes + 255) & ~(size_t)255;
        return p;
    };
    // ---- workspace layout (~196 MB total) ----
    short* WqkvgT = (short*)alloc((size_t)4096 * 1024 * 2);   // 8 MB  [n=4096][k=1024]
    short* WoT    = (short*)alloc((size_t)1024 * 1024 * 2);   // 2 MB  [n=1024][k=1024]
    short* W1T    = (short*)alloc((size_t)4096 * 1024 * 2);   // 8 MB  [n=4096][k=1024]
    short* W2T    = (short*)alloc((size_t)1024 * 4096 * 2);   // 8 MB  [n=1024][k=4096]
    float* biasq  = (float*)alloc((size_t)4096 * 4);
    float* carry  = (float*)alloc((size_t)NCH * 4096 * 4);    // 0.5 MB
    float* sinit  = (float*)alloc((size_t)NCH * 4096 * 4);    // 0.5 MB
    short* bufA   = (short*)alloc((size_t)NROWS * 1024 * 2);  // 32 MB: y -> att -> h
    short* bufB   = (short*)alloc((size_t)NROWS * 4096 * 2);  // 128 MB: qkvg -> ff1
    // x2 lives in d_out (64 MB saved); final GEMM does in-place residual.
    float* x2 = out;
    short* ybuf = bufA;   // LN1 output
    short* att  = bufA;   // scan output (ybuf dead by then)
    short* hbuf = bufA;   // LN2 output (att dead by then)
    short* qkvg = bufB;
    short* ff1  = bufB;   // qkvg dead after scan_pass2
    (void)in_sizes; (void)n_in; (void)out_size;

    if (off > ws_size) return;  // ws too small: fail validation cleanly, not a segfault

    dim3 tb(32, 32);
    // weight prep: transpose + bf16 cast (must rerun every call; ws is poisoned)
    transpose_f32_bf16<<<dim3(32, 32), tb, 0, stream>>>(Wq, WqkvgT + 0 * 1024 * 1024, 1024, 1024);
    transpose_f32_bf16<<<dim3(32, 32), tb, 0, stream>>>(Wk, WqkvgT + 1 * 1024 * 1024, 1024, 1024);
    transpose_f32_bf16<<<dim3(32, 32), tb, 0, stream>>>(Wv, WqkvgT + 2 * 1024 * 1024, 1024, 1024);
    transpose_f32_bf16<<<dim3(32, 32), tb, 0, stream>>>(Wg, WqkvgT + 3 * 1024 * 1024, 1024, 1024);
    transpose_f32_bf16<<<dim3(32, 32), tb, 0, stream>>>(Wo, WoT, 1024, 1024);
    transpose_f32_bf16<<<dim3(128, 32), tb, 0, stream>>>(W1, W1T, 1024, 4096);
    transpose_f32_bf16<<<dim3(32, 128), tb, 0, stream>>>(W2, W2T, 4096, 1024);
    concat_bias<<<16, 256, 0, stream>>>(bq, bk, bv, bg, biasq);

    // LN1: x -> y(bf16)
    ln_kernel<<<NROWS, 256, 0, stream>>>(x, ln1_g, ln1_b, ybuf);

    // QKVG projection (fused bias + sigmoid on G): grid 64x16 = 1024 wg
    gemm_bf16<<<dim3(64, 16), 512, 0, stream>>>(
        ybuf, WqkvgT, biasq, nullptr, nullptr, qkvg, NROWS, 4096, 1024, 0);

    // retention scan
    scan_pass1 <<<NCH * 16, 256, 0, stream>>>(qkvg, dlog, carry);
    scan_combine<<<16, 256, 0, stream>>>(carry, dlog, sinit);
    scan_pass2 <<<NCH * 16, 256, 0, stream>>>(qkvg, dlog, sinit, att);

    // output projection + residual: x2 = x + att@Wo + bo   (x2 == d_out)
    gemm_bf16<<<dim3(64, 4), 512, 0, stream>>>(
        att, WoT, bo, x, x2, nullptr, NROWS, 1024, 1024, 1);

    // LN2: x2 -> h(bf16)
    ln_kernel<<<NROWS, 256, 0, stream>>>(x2, ln2_g, ln2_b, hbuf);

    // FFN: ff1 = gelu(h@W1 + b1)  (bf16)
    gemm_bf16<<<dim3(64, 16), 512, 0, stream>>>(
        hbuf, W1T, b1, nullptr, nullptr, ff1, NROWS, 4096, 1024, 2);

    // out = x2 + ff1@W2 + b2   (in-place residual on d_out)
    gemm_bf16<<<dim3(64, 4), 512, 0, stream>>>(
        ff1, W2T, b2, x2, out, nullptr, NROWS, 1024, 4096, 1);
}